// Round 4
// baseline (120.055 us; speedup 1.0000x reference)
//
#include <hip/hip_runtime.h>
#include <hip/hip_fp16.h>

// out[e] = (dot(h[src],h[dst]) + bias[nid[src]] + bias[nid[dst]]) / (pop[src]*pop[dst])
//
// Pipeline (all in d_ws, rebuilt every call — deterministic):
//   1) convert_h : h f32 -> h16 fp16 (25.6 MB)      [halves gather bytes]
//   2) node_prep : nodeinfo[i] = {1/pop, bias[nid]} (800 KB)
//   3) zero+hist+scan+scatter : counting-sort edges by src>>3 into
//      rec[pos] = {src, dst, e} so src-side gathers become L1/L2-local
//      (mean src multiplicity = 5 -> src fabric traffic 128 MB -> ~30 MB)
//   4) edge_score_sorted : 8 lanes/edge; load1 covers row line 1,
//      load2 line 2; fp32 accumulate; 3-step shfl reduce; out[e] scattered.

#define BUCKET_SHIFT 3   // 8 src nodes per bucket

union H8 {
    float4  f4;
    __half2 h2[4];
};

__device__ inline float dot8(const H8& a, const H8& b) {
    float s = 0.0f;
#pragma unroll
    for (int k = 0; k < 4; ++k) {
        float2 fa = __half22float2(a.h2[k]);
        float2 fb = __half22float2(b.h2[k]);
        s += fa.x * fb.x + fa.y * fb.y;
    }
    return s;
}

__global__ __launch_bounds__(256) void convert_h_kernel(
    const float* __restrict__ h,
    __half*      __restrict__ h16,
    int n_elems)
{
    int i = blockIdx.x * blockDim.x + threadIdx.x;
    int base = i * 8;
    if (base < n_elems) {
        const float4 f0 = *reinterpret_cast<const float4*>(h + base);
        const float4 f1 = *reinterpret_cast<const float4*>(h + base + 4);
        H8 o;
        o.h2[0] = __floats2half2_rn(f0.x, f0.y);
        o.h2[1] = __floats2half2_rn(f0.z, f0.w);
        o.h2[2] = __floats2half2_rn(f1.x, f1.y);
        o.h2[3] = __floats2half2_rn(f1.z, f1.w);
        *reinterpret_cast<float4*>(h16 + base) = o.f4;
    }
}

__global__ __launch_bounds__(256) void node_prep_kernel(
    const float* __restrict__ pop,
    const float* __restrict__ bias,
    const int*   __restrict__ nid,
    float2*      __restrict__ nodeinfo,
    int n_nodes)
{
    int i = blockIdx.x * blockDim.x + threadIdx.x;
    if (i < n_nodes) {
        nodeinfo[i] = make_float2(1.0f / pop[i], bias[nid[i]]);
    }
}

__global__ __launch_bounds__(256) void zero_kernel(
    unsigned* __restrict__ p, int n)
{
    int i = blockIdx.x * blockDim.x + threadIdx.x;
    if (i < n) p[i] = 0u;
}

__global__ __launch_bounds__(256) void hist_kernel(
    const int* __restrict__ src,
    unsigned*  __restrict__ counts,
    int n_edges)
{
    int e = blockIdx.x * blockDim.x + threadIdx.x;
    if (e < n_edges) {
        atomicAdd(&counts[src[e] >> BUCKET_SHIFT], 1u);
    }
}

// single-block exclusive scan over nb (<= ~16K) counters
__global__ __launch_bounds__(1024) void scan_kernel(
    const unsigned* __restrict__ counts,
    unsigned*       __restrict__ cursors,
    int nb)
{
    __shared__ unsigned partial[1024];
    const int tid   = threadIdx.x;
    const int chunk = (nb + 1023) / 1024;
    const int lo    = tid * chunk;
    const int hi    = min(lo + chunk, nb);

    unsigned s = 0;
    for (int i = lo; i < hi; ++i) s += counts[i];
    partial[tid] = s;
    __syncthreads();

    for (int off = 1; off < 1024; off <<= 1) {
        unsigned v = (tid >= off) ? partial[tid - off] : 0u;
        __syncthreads();
        partial[tid] += v;
        __syncthreads();
    }

    unsigned base = (tid == 0) ? 0u : partial[tid - 1];
    for (int i = lo; i < hi; ++i) {
        cursors[i] = base;
        base += counts[i];
    }
}

__global__ __launch_bounds__(256) void scatter_kernel(
    const int* __restrict__ src,
    const int* __restrict__ dst,
    unsigned*  __restrict__ cursors,
    int4*      __restrict__ rec,
    int n_edges)
{
    int e = blockIdx.x * blockDim.x + threadIdx.x;
    if (e < n_edges) {
        const int si = src[e];
        const unsigned pos = atomicAdd(&cursors[si >> BUCKET_SHIFT], 1u);
        rec[pos] = make_int4(si, dst[e], e, 0);
    }
}

__global__ __launch_bounds__(256) void edge_score_sorted_kernel(
    const __half* __restrict__ h16,
    const float2* __restrict__ nodeinfo,
    const int4*   __restrict__ rec,
    float*        __restrict__ out,
    int n_edges)
{
    const int gtid = blockIdx.x * blockDim.x + threadIdx.x;
    const int k    = gtid >> 3;           // one edge per 8 lanes
    const int lane = threadIdx.x & 7;
    if (k >= n_edges) return;

    const int4 r  = rec[k];               // same addr across group -> broadcast
    const int  si = r.x;
    const int  di = r.y;

    // row = 256 B; load1 of the 8 lanes covers line 1, load2 covers line 2
    const __half* ra = h16 + (size_t)si * 128 + lane * 8;
    const __half* rb = h16 + (size_t)di * 128 + lane * 8;

    H8 a0, a1, b0, b1;
    a0.f4 = *reinterpret_cast<const float4*>(ra);
    a1.f4 = *reinterpret_cast<const float4*>(ra + 64);
    b0.f4 = *reinterpret_cast<const float4*>(rb);
    b1.f4 = *reinterpret_cast<const float4*>(rb + 64);

    float part = dot8(a0, b0) + dot8(a1, b1);

    part += __shfl_xor(part, 1);
    part += __shfl_xor(part, 2);
    part += __shfl_xor(part, 4);

    if (lane == 0) {
        const float2 ns = nodeinfo[si];
        const float2 nd = nodeinfo[di];
        out[r.z] = (part + ns.y + nd.y) * (ns.x * nd.x);
    }
}

// ---- fallback paths (ws too small) ----

__global__ __launch_bounds__(256) void edge_score_f16_kernel(
    const __half* __restrict__ h16,
    const float2* __restrict__ nodeinfo,
    const int*    __restrict__ src,
    const int*    __restrict__ dst,
    float*        __restrict__ out,
    int n_edges)
{
    const int gtid = blockIdx.x * blockDim.x + threadIdx.x;
    const int e    = gtid >> 3;
    const int lane = threadIdx.x & 7;
    if (e >= n_edges) return;

    const int si = src[e];
    const int di = dst[e];
    const __half* ra = h16 + (size_t)si * 128 + lane * 8;
    const __half* rb = h16 + (size_t)di * 128 + lane * 8;

    H8 a0, a1, b0, b1;
    a0.f4 = *reinterpret_cast<const float4*>(ra);
    a1.f4 = *reinterpret_cast<const float4*>(ra + 64);
    b0.f4 = *reinterpret_cast<const float4*>(rb);
    b1.f4 = *reinterpret_cast<const float4*>(rb + 64);

    float part = dot8(a0, b0) + dot8(a1, b1);

    part += __shfl_xor(part, 1);
    part += __shfl_xor(part, 2);
    part += __shfl_xor(part, 4);

    if (lane == 0) {
        const float2 ns = nodeinfo[si];
        const float2 nd = nodeinfo[di];
        out[e] = (part + ns.y + nd.y) * (ns.x * nd.x);
    }
}

__global__ __launch_bounds__(256) void edge_score_fallback_kernel(
    const float* __restrict__ h,
    const float* __restrict__ pop,
    const float* __restrict__ bias,
    const int*   __restrict__ src,
    const int*   __restrict__ dst,
    const int*   __restrict__ nid,
    float*       __restrict__ out,
    int n_edges)
{
    const int gtid = blockIdx.x * blockDim.x + threadIdx.x;
    const int e    = gtid >> 4;
    const int lane = threadIdx.x & 15;
    if (e >= n_edges) return;

    const int si = src[e];
    const int di = dst[e];
    const float* ra = h + (size_t)si * 128 + lane * 8;
    const float* rb = h + (size_t)di * 128 + lane * 8;
    const float4 a0 = *reinterpret_cast<const float4*>(ra);
    const float4 a1 = *reinterpret_cast<const float4*>(ra + 4);
    const float4 b0 = *reinterpret_cast<const float4*>(rb);
    const float4 b1 = *reinterpret_cast<const float4*>(rb + 4);

    float part = a0.x * b0.x + a0.y * b0.y + a0.z * b0.z + a0.w * b0.w
               + a1.x * b1.x + a1.y * b1.y + a1.z * b1.z + a1.w * b1.w;

    part += __shfl_xor(part, 1);
    part += __shfl_xor(part, 2);
    part += __shfl_xor(part, 4);
    part += __shfl_xor(part, 8);

    if (lane == 0) {
        const float ipw = (1.0f / pop[si]) * (1.0f / pop[di]);
        const float bb  = bias[nid[si]] + bias[nid[di]];
        out[e] = (part + bb) * ipw;
    }
}

extern "C" void kernel_launch(void* const* d_in, const int* in_sizes, int n_in,
                              void* d_out, int out_size, void* d_ws, size_t ws_size,
                              hipStream_t stream) {
    const float* h    = (const float*)d_in[0];
    const float* pop  = (const float*)d_in[1];
    const float* bias = (const float*)d_in[2];
    const int*   src  = (const int*)d_in[3];
    const int*   dst  = (const int*)d_in[4];
    const int*   nid  = (const int*)d_in[5];
    float*       out  = (float*)d_out;

    const int n_edges = in_sizes[3];
    const int n_nodes = in_sizes[1];
    const int n_elems = in_sizes[0];          // n_nodes * 128
    const int n_buckets = (n_nodes + (1 << BUCKET_SHIFT) - 1) >> BUCKET_SHIFT;

    auto align256 = [](size_t x) { return (x + 255) & ~(size_t)255; };

    const size_t h16_bytes  = align256((size_t)n_elems * sizeof(__half));
    const size_t info_bytes = align256((size_t)n_nodes * sizeof(float2));
    const size_t cnt_bytes  = align256((size_t)n_buckets * sizeof(unsigned));
    const size_t rec_bytes  = align256((size_t)n_edges * sizeof(int4));
    const size_t full_bytes = h16_bytes + info_bytes + 2 * cnt_bytes + rec_bytes;

    if (ws_size >= full_bytes) {
        char* p = (char*)d_ws;
        __half*   h16      = (__half*)p;              p += h16_bytes;
        float2*   nodeinfo = (float2*)p;              p += info_bytes;
        unsigned* counts   = (unsigned*)p;            p += cnt_bytes;
        unsigned* cursors  = (unsigned*)p;            p += cnt_bytes;
        int4*     rec      = (int4*)p;

        int cgrid = (n_elems / 8 + 255) / 256;
        convert_h_kernel<<<cgrid, 256, 0, stream>>>(h, h16, n_elems);

        int pgrid = (n_nodes + 255) / 256;
        node_prep_kernel<<<pgrid, 256, 0, stream>>>(pop, bias, nid, nodeinfo, n_nodes);

        zero_kernel<<<(n_buckets + 255) / 256, 256, 0, stream>>>(counts, n_buckets);

        int egrid = (n_edges + 255) / 256;
        hist_kernel<<<egrid, 256, 0, stream>>>(src, counts, n_edges);

        scan_kernel<<<1, 1024, 0, stream>>>(counts, cursors, n_buckets);

        scatter_kernel<<<egrid, 256, 0, stream>>>(src, dst, cursors, rec, n_edges);

        int grid = ((n_edges * 8) + 255) / 256;
        edge_score_sorted_kernel<<<grid, 256, 0, stream>>>(h16, nodeinfo, rec,
                                                           out, n_edges);
    } else if (ws_size >= h16_bytes + info_bytes) {
        __half* h16      = (__half*)d_ws;
        float2* nodeinfo = (float2*)((char*)d_ws + h16_bytes);

        int cgrid = (n_elems / 8 + 255) / 256;
        convert_h_kernel<<<cgrid, 256, 0, stream>>>(h, h16, n_elems);

        int pgrid = (n_nodes + 255) / 256;
        node_prep_kernel<<<pgrid, 256, 0, stream>>>(pop, bias, nid, nodeinfo, n_nodes);

        int grid = ((n_edges * 8) + 255) / 256;
        edge_score_f16_kernel<<<grid, 256, 0, stream>>>(h16, nodeinfo, src, dst,
                                                        out, n_edges);
    } else {
        int grid = ((n_edges * 16) + 255) / 256;
        edge_score_fallback_kernel<<<grid, 256, 0, stream>>>(h, pop, bias, src, dst, nid,
                                                             out, n_edges);
    }
}

// Round 5
// 54.886 us; speedup vs baseline: 2.1873x; 2.1873x over previous
//
#include <hip/hip_runtime.h>
#include <hip/hip_fp16.h>

// out[e] = (dot(h[src],h[dst]) + bias[nid[src]] + bias[nid[dst]]) / (pop[src]*pop[dst])
//
// Two kernels:
//   1) prep_kernel: fused
//        - h (f32, 51.2 MB) -> h16 (fp16, 25.6 MB)   [halves random-gather bytes]
//        - nodeinfo[i] = {1/pop[i], bias[nid[i]]}    (800 KB, L2-resident)
//   2) edge_score_f16: 8 lanes/edge; each lane 16 B per row; the group's two
//      loads cover the row's two 128-B lines exactly. fp32 accumulate,
//      3-step shfl_xor reduce. Index loads / out stores are nontemporal so
//      the single-use streams don't evict h16 (mean reuse ~10x/row).

union H8 {
    float4  f4;
    __half2 h2[4];
};

__device__ inline float dot8(const H8& a, const H8& b) {
    float s = 0.0f;
#pragma unroll
    for (int k = 0; k < 4; ++k) {
        float2 fa = __half22float2(a.h2[k]);
        float2 fb = __half22float2(b.h2[k]);
        s += fa.x * fb.x + fa.y * fb.y;
    }
    return s;
}

__global__ __launch_bounds__(256) void prep_kernel(
    const float* __restrict__ h,
    __half*      __restrict__ h16,
    const float* __restrict__ pop,
    const float* __restrict__ bias,
    const int*   __restrict__ nid,
    float2*      __restrict__ nodeinfo,
    int n_elems,                       // n_nodes * 128
    int n_nodes,
    int conv_blocks)                   // blocks devoted to conversion
{
    if (blockIdx.x < (unsigned)conv_blocks) {
        int i = blockIdx.x * blockDim.x + threadIdx.x;
        int base = i * 8;
        if (base < n_elems) {
            const float4 f0 = *reinterpret_cast<const float4*>(h + base);
            const float4 f1 = *reinterpret_cast<const float4*>(h + base + 4);
            H8 o;
            o.h2[0] = __floats2half2_rn(f0.x, f0.y);
            o.h2[1] = __floats2half2_rn(f0.z, f0.w);
            o.h2[2] = __floats2half2_rn(f1.x, f1.y);
            o.h2[3] = __floats2half2_rn(f1.z, f1.w);
            *reinterpret_cast<float4*>(h16 + base) = o.f4;
        }
    } else {
        int i = (blockIdx.x - conv_blocks) * blockDim.x + threadIdx.x;
        if (i < n_nodes) {
            nodeinfo[i] = make_float2(1.0f / pop[i], bias[nid[i]]);
        }
    }
}

__global__ __launch_bounds__(256) void edge_score_f16_kernel(
    const __half* __restrict__ h16,
    const float2* __restrict__ nodeinfo,
    const int*    __restrict__ src,
    const int*    __restrict__ dst,
    float*        __restrict__ out,
    int n_edges)
{
    const int gtid = blockIdx.x * blockDim.x + threadIdx.x;
    const int e    = gtid >> 3;           // one edge per 8 lanes
    const int lane = threadIdx.x & 7;
    if (e >= n_edges) return;

    const int si = __builtin_nontemporal_load(src + e);
    const int di = __builtin_nontemporal_load(dst + e);

    // row = 128 halves = 256 B; group load1 covers line 1, load2 line 2
    const __half* ra = h16 + (size_t)si * 128 + lane * 8;
    const __half* rb = h16 + (size_t)di * 128 + lane * 8;

    H8 a0, a1, b0, b1;
    a0.f4 = *reinterpret_cast<const float4*>(ra);
    a1.f4 = *reinterpret_cast<const float4*>(ra + 64);
    b0.f4 = *reinterpret_cast<const float4*>(rb);
    b1.f4 = *reinterpret_cast<const float4*>(rb + 64);

    float part = dot8(a0, b0) + dot8(a1, b1);

    part += __shfl_xor(part, 1);
    part += __shfl_xor(part, 2);
    part += __shfl_xor(part, 4);

    if (lane == 0) {
        const float2 ns = nodeinfo[si];
        const float2 nd = nodeinfo[di];
        __builtin_nontemporal_store((part + ns.y + nd.y) * (ns.x * nd.x), out + e);
    }
}

// ---- fallback (ws too small): direct f32 path with scalar gathers ----

__global__ __launch_bounds__(256) void edge_score_fallback_kernel(
    const float* __restrict__ h,
    const float* __restrict__ pop,
    const float* __restrict__ bias,
    const int*   __restrict__ src,
    const int*   __restrict__ dst,
    const int*   __restrict__ nid,
    float*       __restrict__ out,
    int n_edges)
{
    const int gtid = blockIdx.x * blockDim.x + threadIdx.x;
    const int e    = gtid >> 4;
    const int lane = threadIdx.x & 15;
    if (e >= n_edges) return;

    const int si = src[e];
    const int di = dst[e];
    const float* ra = h + (size_t)si * 128 + lane * 8;
    const float* rb = h + (size_t)di * 128 + lane * 8;
    const float4 a0 = *reinterpret_cast<const float4*>(ra);
    const float4 a1 = *reinterpret_cast<const float4*>(ra + 4);
    const float4 b0 = *reinterpret_cast<const float4*>(rb);
    const float4 b1 = *reinterpret_cast<const float4*>(rb + 4);

    float part = a0.x * b0.x + a0.y * b0.y + a0.z * b0.z + a0.w * b0.w
               + a1.x * b1.x + a1.y * b1.y + a1.z * b1.z + a1.w * b1.w;

    part += __shfl_xor(part, 1);
    part += __shfl_xor(part, 2);
    part += __shfl_xor(part, 4);
    part += __shfl_xor(part, 8);

    if (lane == 0) {
        const float ipw = (1.0f / pop[si]) * (1.0f / pop[di]);
        const float bb  = bias[nid[si]] + bias[nid[di]];
        out[e] = (part + bb) * ipw;
    }
}

extern "C" void kernel_launch(void* const* d_in, const int* in_sizes, int n_in,
                              void* d_out, int out_size, void* d_ws, size_t ws_size,
                              hipStream_t stream) {
    const float* h    = (const float*)d_in[0];
    const float* pop  = (const float*)d_in[1];
    const float* bias = (const float*)d_in[2];
    const int*   src  = (const int*)d_in[3];
    const int*   dst  = (const int*)d_in[4];
    const int*   nid  = (const int*)d_in[5];
    float*       out  = (float*)d_out;

    const int n_edges = in_sizes[3];
    const int n_nodes = in_sizes[1];
    const int n_elems = in_sizes[0];          // n_nodes * 128

    auto align256 = [](size_t x) { return (x + 255) & ~(size_t)255; };
    const size_t h16_bytes  = align256((size_t)n_elems * sizeof(__half));
    const size_t info_bytes = align256((size_t)n_nodes * sizeof(float2));

    if (ws_size >= h16_bytes + info_bytes) {
        __half* h16      = (__half*)d_ws;
        float2* nodeinfo = (float2*)((char*)d_ws + h16_bytes);

        const int conv_blocks = (n_elems / 8 + 255) / 256;
        const int prep_blocks = (n_nodes + 255) / 256;
        prep_kernel<<<conv_blocks + prep_blocks, 256, 0, stream>>>(
            h, h16, pop, bias, nid, nodeinfo, n_elems, n_nodes, conv_blocks);

        int grid = ((n_edges * 8) + 255) / 256;   // 8 lanes per edge
        edge_score_f16_kernel<<<grid, 256, 0, stream>>>(h16, nodeinfo, src, dst,
                                                        out, n_edges);
    } else {
        int grid = ((n_edges * 16) + 255) / 256;
        edge_score_fallback_kernel<<<grid, 256, 0, stream>>>(h, pop, bias, src, dst, nid,
                                                             out, n_edges);
    }
}